// Round 8
// baseline (179.176 us; speedup 1.0000x reference)
//
#include <hip/hip_runtime.h>
#include <math.h>

// ---------------- problem constants ----------------
#define BB   16      // batch
#define TT   50      // targets per image
#define BT   (BB*TT) // 800
#define NCLS 80
#define IMGF 608.0f

#define H0 76
#define H1 38
#define H2 19
#define N0 277248   // 16*3*76*76 cells
#define N1 69312    // 16*3*38*38
#define N2 17328    // 16*3*19*19
#define NTOT (N0+N1+N2)   // 363888

// float4 counts per scale (N*85/4, all divisible by 4 since N%4==0)
#define F0 5891520
#define F1 1472880
#define F2 368220

// stream blocks per scale — chosen so per-block work is uniform (~3683 float4)
#define SB0 1600
#define SB1 400
#define SB2 100
#define NSTREAM (SB0+SB1+SB2)      // 2100

#define NPOS (3*BT)                 // 2400 (scale,order) items
#define NPOSBLK (NPOS/4)            // 600 blocks, one wave per item
#define NBLK (NPOSBLK + NSTREAM)    // 2700; pos blocks FIRST (latency hides under stream)

__constant__ float c_anchors[3][3][2] = {
    {{12.f,16.f},{19.f,36.f},{40.f,28.f}},
    {{36.f,75.f},{76.f,55.f},{72.f,146.f}},
    {{142.f,110.f},{192.f,243.f},{459.f,401.f}}};
__constant__ int c_H[3] = {H0, H1, H2};

__device__ __forceinline__ float sigmoidf_(float x) { return 1.0f / (1.0f + expf(-x)); }
__device__ __forceinline__ float clipf_(float x, float lo, float hi) {
    return fminf(fmaxf(x, lo), hi);
}

__device__ __forceinline__ float iou4(float ax, float ay, float aw, float ah,
                                      float bx, float by, float bw, float bh) {
    float ax1 = ax - aw * 0.5f, ay1 = ay - ah * 0.5f;
    float ax2 = ax + aw * 0.5f, ay2 = ay + ah * 0.5f;
    float bx1 = bx - bw * 0.5f, by1 = by - bh * 0.5f;
    float bx2 = bx + bw * 0.5f, by2 = by + bh * 0.5f;
    float iw = fmaxf(fminf(ax2, bx2) - fmaxf(ax1, bx1), 0.f);
    float ih = fmaxf(fminf(ay2, by2) - fmaxf(ay1, by1), 0.f);
    float inter = iw * ih;
    float uni = (ax2 - ax1) * (ay2 - ay1) + (bx2 - bx1) * (by2 - by1) - inter + 1e-7f;
    return inter / uni;
}

// anchor match + cell for one (scale, target row). returns -1 if invalid target
__device__ __forceinline__ int target_cell(const float* tr, int s, float& cx, float& cy,
                                           float& w, float& h, int& best, int& gxi, int& gyi) {
    float t4 = tr[4];
    if (!(t4 > 0.f)) return -1;
    cx = clipf_(tr[0], 0.f, 1.f);
    cy = clipf_(tr[1], 0.f, 1.f);
    w  = clipf_(tr[2], 0.f, 1.f);
    h  = clipf_(tr[3], 0.f, 1.f);
    best = 0;
    float bi = -1e30f;
    #pragma unroll
    for (int a = 0; a < 3; a++) {
        float aw = c_anchors[s][a][0] / IMGF;
        float ah = c_anchors[s][a][1] / IMGF;
        float v = iou4(0.5f, 0.5f, aw, ah, cx, cy, w, h);
        if (v > bi) { bi = v; best = a; }  // first-max == jnp.argmax
    }
    int H = c_H[s];
    gxi = (int)(cx * (float)H); gxi = min(max(gxi, 0), H - 1);
    gyi = (int)(cy * (float)H); gyi = min(max(gyi, 0), H - 1);
    return 0;
}

// ---- main kernel ----
// blocks [0,NPOSBLK): positive items, one wave each (latency-bound, scheduled first).
// blocks [NPOSBLK,NBLK): COALESCED float4 stream over one scale's entire pred;
//   channel-4 elements selected via r = (4*i)%85 in [1,4] -> component 4-r.
//   (R7 post-mortem: stride-340 gather = 64 lines/wave-instr, measured 434 GB/s;
//   streaming all 124 MB coalesced is 2.8x faster despite 5x the bytes.)
__global__ __launch_bounds__(256) void k_main(const float* __restrict__ p0,
                                              const float* __restrict__ p1,
                                              const float* __restrict__ p2,
                                              const float* __restrict__ targets,
                                              float* __restrict__ noobj_part,   // [NSTREAM]
                                              float* __restrict__ pos_part) {   // [NPOS*5]
    int blk = blockIdx.x;
    int lane = threadIdx.x & 63;
    int wv = threadIdx.x >> 6;

    if (blk >= NPOSBLK) {
        // ---------- coalesced no-object BCE stream ----------
        int sblk = blk - NPOSBLK;
        const float4* p4; unsigned nf4; int local, nb;
        if (sblk < SB0)            { p4 = (const float4*)p0; nf4 = F0; local = sblk;            nb = SB0; }
        else if (sblk < SB0 + SB1) { p4 = (const float4*)p1; nf4 = F1; local = sblk - SB0;      nb = SB1; }
        else                       { p4 = (const float4*)p2; nf4 = F2; local = sblk - SB0 - SB1; nb = SB2; }

        float acc = 0.f;
        unsigned stride = (unsigned)nb * 256u;
        for (unsigned i = (unsigned)local * 256u + threadIdx.x; i < nf4; i += stride) {
            float4 v = p4[i];
            unsigned r = (i * 4u) % 85u;            // flat float index mod 85
            if (r >= 1u && r <= 4u) {               // component 4-r is channel 4
                unsigned k = 4u - r;
                float lg = (k == 0u) ? v.x : (k == 1u) ? v.y : (k == 2u) ? v.z : v.w;
                float p = clipf_(sigmoidf_(lg), 1e-10f, 1.0f);
                acc += -log1pf(-p);
            }
        }
        #pragma unroll
        for (int off = 32; off > 0; off >>= 1) acc += __shfl_xor(acc, off, 64);
        __shared__ float sm[4];
        if (lane == 0) sm[wv] = acc;
        __syncthreads();
        if (threadIdx.x == 0)
            noobj_part[sblk] = sm[0] + sm[1] + sm[2] + sm[3];
    } else {
        // ---------- positive cells: one WAVE per (scale, order) ----------
        int item = blk * 4 + wv;                    // < 2400
        int s = item / BT;
        int order = item % BT;
        int b = order / TT, t = order % TT;

        float v_coord = 0.f, v_obj = 0.f, v_noadj = 0.f, v_cls = 0.f, v_np = 0.f;

        const float* tr = targets + order * 85;
        float cx, cy, w, h; int best, gxi, gyi;
        if (target_cell(tr, s, cx, cy, w, h, best, gxi, gyi) == 0) {  // wave-uniform
            int H = c_H[s];
            int flat = ((b * 3 + best) * H + gyi) * H + gxi;

            // inline last-write-wins: any LATER valid target in this image on same cell?
            bool lost = false;
            int tp = t + 1 + lane;
            if (tp < TT) {
                const float* tr2 = targets + (b * TT + tp) * 85;
                float cx2, cy2, w2, h2; int best2, gxi2, gyi2;
                if (target_cell(tr2, s, cx2, cy2, w2, h2, best2, gxi2, gyi2) == 0) {
                    int flat2 = ((b * 3 + best2) * H + gyi2) * H + gxi2;
                    lost = (flat2 == flat);
                }
            }
            if (__ballot(lost) == 0ull) {   // this order wins the cell
                const float* pred = (s == 0) ? p0 : (s == 1) ? p1 : p2;
                const float* pc = pred + (long long)flat * 85;

                float px = sigmoidf_(pc[0]);
                float py = sigmoidf_(pc[1]);
                float bx = clipf_((px + (float)gxi) / (float)H, 0.f, 1.f);
                float by = clipf_((py + (float)gyi) / (float)H, 0.f, 1.f);
                float aw = c_anchors[s][best][0], ah = c_anchors[s][best][1];
                float bwv = clipf_(expf(clipf_(pc[2], -10.f, 10.f)) * aw / IMGF, 0.f, 1.f);
                float bhv = clipf_(expf(clipf_(pc[3], -10.f, 10.f)) * ah / IMGF, 0.f, 1.f);
                float iou = iou4(bx, by, bwv, bhv, cx, cy, w, h);

                float p = clipf_(sigmoidf_(pc[4]), 1e-10f, 1.0f);

                // class BCE split across lanes: lane k -> class k (+ class k+64 if k<16)
                float pcv = clipf_(sigmoidf_(pc[5 + lane]), 1e-10f, 1.0f);
                float tc  = clipf_(tr[5 + lane], 0.f, 1.f);
                float cl  = -(tc * logf(pcv) + (1.f - tc) * log1pf(-pcv));
                if (lane < NCLS - 64) {
                    float pcv2 = clipf_(sigmoidf_(pc[5 + 64 + lane]), 1e-10f, 1.0f);
                    float tc2  = clipf_(tr[5 + 64 + lane], 0.f, 1.f);
                    cl += -(tc2 * logf(pcv2) + (1.f - tc2) * log1pf(-pcv2));
                }
                #pragma unroll
                for (int off = 32; off > 0; off >>= 1) cl += __shfl_xor(cl, off, 64);

                v_coord = 1.f - iou;
                v_obj   = -logf(p);
                v_noadj = -log1pf(-p);
                v_cls   = cl;
                v_np    = 1.f;
            }
        }

        // lane 0 writes 5 partials (zeros if invalid/lost; ws is re-poisoned each launch)
        if (lane == 0) {
            float* dst = pos_part + (long long)item * 5;
            dst[0] = v_coord; dst[1] = v_obj; dst[2] = v_noadj;
            dst[3] = v_cls;   dst[4] = v_np;
        }
    }
}

// ---- kernel D: reduce partials + final combine ----
__global__ __launch_bounds__(256) void k_final(const float* __restrict__ noobj_part,
                                               const float* __restrict__ pos_part,
                                               float* __restrict__ out) {
    float nsum[3] = {0.f, 0.f, 0.f};
    for (int i = threadIdx.x; i < NSTREAM; i += 256) {
        float v = noobj_part[i];
        if (i < SB0)            nsum[0] += v;
        else if (i < SB0 + SB1) nsum[1] += v;
        else                    nsum[2] += v;
    }
    float ps[3][5] = {};
    for (int i = threadIdx.x; i < NPOS; i += 256) {
        int s = i / BT;
        #pragma unroll
        for (int q = 0; q < 5; q++) ps[s][q] += pos_part[i * 5 + q];
    }

    __shared__ float red[18][256];
    #pragma unroll
    for (int s = 0; s < 3; s++) {
        red[s][threadIdx.x] = nsum[s];
        #pragma unroll
        for (int q = 0; q < 5; q++) red[3 + s * 5 + q][threadIdx.x] = ps[s][q];
    }
    __syncthreads();
    for (int off = 128; off > 0; off >>= 1) {
        if (threadIdx.x < off) {
            #pragma unroll
            for (int r = 0; r < 18; r++)
                red[r][threadIdx.x] += red[r][threadIdx.x + off];
        }
        __syncthreads();
    }
    if (threadIdx.x == 0) {
        const float ncell[3] = {(float)N0, (float)N1, (float)N2};
        float coord = 0.f, conf = 0.f, cls = 0.f;
        #pragma unroll
        for (int s = 0; s < 3; s++) {
            float noobjTot = red[s][0];
            float co    = red[3 + s * 5 + 0][0];
            float ob    = red[3 + s * 5 + 1][0];
            float noadj = red[3 + s * 5 + 2][0];
            float cl    = red[3 + s * 5 + 3][0];
            float npos  = red[3 + s * 5 + 4][0];
            float nneg = ncell[s] - npos;
            float dn = fmaxf(npos, 1.f);
            conf += ob / dn + 0.5f * (noobjTot - noadj) / fmaxf(nneg, 1.f);
            if (npos > 0.f) {
                coord += co / dn;
                cls   += cl / fmaxf(npos * (float)NCLS, 1.f);
            }
        }
        out[0] = 5.0f * coord + conf + 1.0f * cls;
        out[1] = coord;
        out[2] = conf;
        out[3] = cls;
    }
}

extern "C" void kernel_launch(void* const* d_in, const int* in_sizes, int n_in,
                              void* d_out, int out_size, void* d_ws, size_t ws_size,
                              hipStream_t stream) {
    const float* p0 = (const float*)d_in[0];
    const float* p1 = (const float*)d_in[1];
    const float* p2 = (const float*)d_in[2];
    const float* tg = (const float*)d_in[3];
    float* out = (float*)d_out;

    char* ws = (char*)d_ws;
    float* noobj_part = (float*)ws;              // NSTREAM floats (8400 B)
    float* pos_part   = (float*)(ws + 16384);    // NPOS*5 floats (48000 B)

    k_main<<<NBLK, 256, 0, stream>>>(p0, p1, p2, tg, noobj_part, pos_part);
    k_final<<<1, 256, 0, stream>>>(noobj_part, pos_part, out);
}